// Round 1
// baseline (7965.910 us; speedup 1.0000x reference)
//
#include <hip/hip_runtime.h>

#define B 16
#define D 256
#define T 4096
#define NQ 8
#define BINS 1024
#define TOK 32        // tokens per block
#define RS 260        // LDS row stride (floats): float4-aligned, benign bank pattern

#define OFF_C  ((size_t)B * D * T)            // quantized elems = 16777216
#define OFF_BW (OFF_C + (size_t)NQ * B * T)   // + codes 524288 -> 17301504
#define OFF_L  (OFF_BW + 1)

// ---------------- codebook norms (f64, exact-ish) ----------------
__global__ __launch_bounds__(256) void cbnorm_kernel(const float* __restrict__ cb,
                                                     double* __restrict__ cbn)
{
    const int wave = threadIdx.x >> 6;
    const int lane = threadIdx.x & 63;
    const int bin = blockIdx.x * 4 + wave;          // 0..8191 (q*1024+k)
    const float4 v = *(const float4*)&cb[(size_t)bin * D + lane * 4];
    double a = (double)v.x * v.x + (double)v.y * v.y
             + (double)v.z * v.z + (double)v.w * v.w;
    #pragma unroll
    for (int off = 32; off >= 1; off >>= 1)
        a += __shfl_xor(a, off, 64);
    if (lane == 0) cbn[bin] = a;
}

// ---------------- fused RVQ: all 8 stages per token tile ----------------
__global__ __launch_bounds__(256, 2) void rvq_main(
    const float* __restrict__ x, const float* __restrict__ cb,
    const double* __restrict__ cbn, float* __restrict__ out,
    double* __restrict__ lpart)
{
    __shared__ float  res[TOK][RS];
    __shared__ float  qnt[TOK][RS];
    __shared__ double bestv[TOK][16];
    __shared__ int    besti[TOK][16];
    __shared__ int    idxs[TOK];

    const int tid = threadIdx.x;
    const int bid = blockIdx.x;
    const int b  = bid >> 7;              // / (T/TOK) = /128
    const int t0 = (bid & 127) * TOK;

    // load x tile [32 tok][256 d] (coalesced 128B segments along t)
    const float* xb = x + (size_t)b * D * T + t0;
    #pragma unroll
    for (int it = 0; it < 32; ++it) {
        const int d  = it * 8 + (tid >> 5);
        const int tk = tid & 31;
        res[tk][d] = xb[(size_t)d * T + tk];
        qnt[tk][d] = 0.0f;
    }
    __syncthreads();

    const int tg = tid & 15;   // token group: owns tokens tg and tg+16
    const int bg = tid >> 4;   // bin group 0..15 (8 bins per chunk each)
    double lacc = 0.0;

    for (int q = 0; q < NQ; ++q) {
        const float*  cbq = cb  + (size_t)q * BINS * D;
        const double* cnq = cbn + (size_t)q * BINS;

        double bv0 = 1e300, bv1 = 1e300;
        int bi0 = 0, bi1 = 0;

        for (int iter = 0; iter < 8; ++iter) {
            const int binbase = iter * 128 + bg * 8;
            double a0[8], a1[8];
            #pragma unroll
            for (int j = 0; j < 8; ++j) { a0[j] = 0.0; a1[j] = 0.0; }

            for (int d = 0; d < D; d += 4) {
                const float4 r0 = *(const float4*)&res[tg][d];
                const float4 r1 = *(const float4*)&res[tg + 16][d];
                const double r00 = r0.x, r01 = r0.y, r02 = r0.z, r03 = r0.w;
                const double r10 = r1.x, r11 = r1.y, r12 = r1.z, r13 = r1.w;
                #pragma unroll
                for (int j = 0; j < 8; ++j) {
                    const float4 c = *(const float4*)&cbq[(size_t)(binbase + j) * D + d];
                    const double c0 = c.x, c1 = c.y, c2 = c.z, c3 = c.w;
                    a0[j] = fma(r00, c0, a0[j]); a0[j] = fma(r01, c1, a0[j]);
                    a0[j] = fma(r02, c2, a0[j]); a0[j] = fma(r03, c3, a0[j]);
                    a1[j] = fma(r10, c0, a1[j]); a1[j] = fma(r11, c1, a1[j]);
                    a1[j] = fma(r12, c2, a1[j]); a1[j] = fma(r13, c3, a1[j]);
                }
            }
            #pragma unroll
            for (int j = 0; j < 8; ++j) {
                const int bin = binbase + j;
                const double qn = cnq[bin];
                const double s0 = fma(-2.0, a0[j], qn);   // dist - ||r||^2 (const/token)
                const double s1 = fma(-2.0, a1[j], qn);
                if (s0 < bv0) { bv0 = s0; bi0 = bin; }
                if (s1 < bv1) { bv1 = s1; bi1 = bin; }
            }
        }
        bestv[tg][bg]      = bv0;  besti[tg][bg]      = bi0;
        bestv[tg + 16][bg] = bv1;  besti[tg + 16][bg] = bi1;
        __syncthreads();

        // per-token argmin across 16 bin-groups, lowest-index tie-break (np.argmin)
        if (tid < TOK) {
            double bv = bestv[tid][0]; int bi = besti[tid][0];
            #pragma unroll
            for (int g = 1; g < 16; ++g) {
                const double v = bestv[tid][g]; const int ii = besti[tid][g];
                if (v < bv || (v == bv && ii < bi)) { bv = v; bi = ii; }
            }
            idxs[tid] = bi;
            out[OFF_C + (size_t)q * B * T + (size_t)b * T + t0 + tid] = (float)bi;
        }
        __syncthreads();

        // faithful straight-through update: e=q-r; qst=r+e; r-=qst; quant+=qst
        const int tku = tid >> 3;
        const int d0  = (tid & 7) * 32;
        const float* crow = cbq + (size_t)idxs[tku] * D;
        #pragma unroll
        for (int i = 0; i < 8; ++i) {
            const int d = d0 + i * 4;
            const float4 qv = *(const float4*)&crow[d];
            float4 r = *(float4*)&res[tku][d];
            float4 g = *(float4*)&qnt[tku][d];
            float e, qst, dd;
            e = qv.x - r.x; qst = r.x + e; dd = qst - r.x;
            lacc = fma((double)dd, (double)dd, lacc); g.x += qst; r.x = r.x - qst;
            e = qv.y - r.y; qst = r.y + e; dd = qst - r.y;
            lacc = fma((double)dd, (double)dd, lacc); g.y += qst; r.y = r.y - qst;
            e = qv.z - r.z; qst = r.z + e; dd = qst - r.z;
            lacc = fma((double)dd, (double)dd, lacc); g.z += qst; r.z = r.z - qst;
            e = qv.w - r.w; qst = r.w + e; dd = qst - r.w;
            lacc = fma((double)dd, (double)dd, lacc); g.w += qst; r.w = r.w - qst;
            *(float4*)&res[tku][d] = r;
            *(float4*)&qnt[tku][d] = g;
        }
        __syncthreads();
    }

    // write quantized [B,D,T] (coalesced 128B segments along t)
    #pragma unroll
    for (int it = 0; it < 32; ++it) {
        const int d  = it * 8 + (tid >> 5);
        const int tk = tid & 31;
        out[(size_t)b * D * T + (size_t)d * T + t0 + tk] = qnt[tk][d];
    }

    // deterministic per-block loss partial (reuse bestv storage as scratch)
    double* lr = &bestv[0][0];     // 512 doubles available
    lr[tid] = lacc;
    __syncthreads();
    for (int s2 = 128; s2 >= 1; s2 >>= 1) {
        if (tid < s2) lr[tid] += lr[tid + s2];
        __syncthreads();
    }
    if (tid == 0) lpart[bid] = lr[0];
}

// ---------------- finalize: loss mean + bandwidth scalar ----------------
__global__ __launch_bounds__(256) void finalize_kernel(
    const double* __restrict__ lpart, int nblk,
    const int* __restrict__ srp, float* __restrict__ out)
{
    __shared__ double sh[256];
    double a = 0.0;
    for (int i = threadIdx.x; i < nblk; i += 256) a += lpart[i];
    sh[threadIdx.x] = a;
    __syncthreads();
    for (int s = 128; s >= 1; s >>= 1) {
        if (threadIdx.x < s) sh[threadIdx.x] += sh[threadIdx.x + s];
        __syncthreads();
    }
    if (threadIdx.x == 0) {
        out[OFF_L]  = (float)(sh[0] / ((double)NQ * B * T * D));
        out[OFF_BW] = (float)((double)NQ * 10.0 * (double)srp[0] / 1000.0);
    }
}

extern "C" void kernel_launch(void* const* d_in, const int* in_sizes, int n_in,
                              void* d_out, int out_size, void* d_ws, size_t ws_size,
                              hipStream_t stream)
{
    const float* x  = (const float*)d_in[0];
    const float* cb = (const float*)d_in[1];
    const int*   sr = (const int*)d_in[2];
    float* out = (float*)d_out;
    double* cbn   = (double*)d_ws;            // 8192 doubles
    double* lpart = cbn + NQ * BINS;          // 2048 doubles

    hipLaunchKernelGGL(cbnorm_kernel, dim3(NQ * BINS / 4), dim3(256), 0, stream, cb, cbn);
    hipLaunchKernelGGL(rvq_main, dim3(B * (T / TOK)), dim3(256), 0, stream, x, cb, cbn, out, lpart);
    hipLaunchKernelGGL(finalize_kernel, dim3(1), dim3(256), 0, stream,
                       lpart, B * (T / TOK), sr, out);
}